// Round 1
// 219.640 us; speedup vs baseline: 1.0039x; 1.0039x over previous
//
#include <hip/hip_runtime.h>

// WavUnPacking: x (8,256,128,128) f32 -> out (8,64,256,256) f32
// Channel quadrants (ll,lh,hl,hh), Haar inverse butterfly into 2x2 blocks.
//
// R2 layout: one WAVE = one (b,c) x one input row-pair (2r, 2r+1) x all 128 cols.
//   loads : 4 x dwordx4 (ll,lh,hl,hh), 16 B/lane -> 1 KiB dense per wave instr
//           (lanes 0-31 cover input row 2r, lanes 32-63 row 2r+1 -- contiguous)
//   LDS   : butterfly results staged in output-linear order (4 out rows x 1 KiB),
//           writes stride-32B (2-way alias, free per m136), reads stride-16B clean
//   stores: 4 x dwordx4, 16 B/lane -> 1 KiB dense per wave instr (one out row each)
// Every VMEM op is now a dense contiguous 1 KiB wave transaction on both sides,
// matching the measured 6.29 TB/s float4-copy recipe (R1 loads were 8 B/lane).

typedef float v4f __attribute__((ext_vector_type(4)));

__global__ __launch_bounds__(256) void wav_unpack_kernel(
    const float* __restrict__ x, float* __restrict__ out) {
    constexpr int Q = 64 * 128 * 128;        // quadrant stride = 1,048,576 floats
    __shared__ float tile[4 * 1024];         // 4 waves x (4 out rows x 256 floats)

    const int tid  = threadIdx.x;
    const int lane = tid & 63;
    const int wib  = tid >> 6;               // wave in block
    const int wid  = (blockIdx.x << 2) | wib;
    const int r    = wid & 63;               // input row-pair index (rows 2r, 2r+1)
    const int bc   = wid >> 6;               // b*64 + c
    const int b    = bc >> 6;

    // input channel = b*256 + c = bc + 192*b; chan stride 16384; rows 2r..2r+1
    // flat lane offset 4*lane spans both rows (row stride 128 floats)
    const int in_base = (bc + 192 * b) * 16384 + (r << 8) + (lane << 2);

    const v4f ll = __builtin_nontemporal_load((const v4f*)(x + in_base));
    const v4f lh = __builtin_nontemporal_load((const v4f*)(x + in_base + Q));
    const v4f hl = __builtin_nontemporal_load((const v4f*)(x + in_base + 2 * Q));
    const v4f hh = __builtin_nontemporal_load((const v4f*)(x + in_base + 3 * Q));

    // Per input col w: e00,e01 -> out row 2h cols 2w,2w+1; e10,e11 -> row 2h+1.
    v4f Tlo, Thi, Blo, Bhi;   // T = out row 2h (8 floats), B = out row 2h+1
    {
        float a, s, c, d;
        a = ll.x + lh.x; s = hl.x + hh.x; c = ll.x - lh.x; d = hl.x - hh.x;
        Tlo.x = 0.5f * (a + s); Tlo.y = 0.5f * (a - s);
        Blo.x = 0.5f * (c + d); Blo.y = 0.5f * (c - d);
        a = ll.y + lh.y; s = hl.y + hh.y; c = ll.y - lh.y; d = hl.y - hh.y;
        Tlo.z = 0.5f * (a + s); Tlo.w = 0.5f * (a - s);
        Blo.z = 0.5f * (c + d); Blo.w = 0.5f * (c - d);
        a = ll.z + lh.z; s = hl.z + hh.z; c = ll.z - lh.z; d = hl.z - hh.z;
        Thi.x = 0.5f * (a + s); Thi.y = 0.5f * (a - s);
        Bhi.x = 0.5f * (c + d); Bhi.y = 0.5f * (c - d);
        a = ll.w + lh.w; s = hl.w + hh.w; c = ll.w - lh.w; d = hl.w - hh.w;
        Thi.z = 0.5f * (a + s); Thi.w = 0.5f * (a - s);
        Bhi.z = 0.5f * (c + d); Bhi.w = 0.5f * (c - d);
    }

    // Stage into LDS in output-linear order.
    // lane < 32 computed input row 2r   -> tile rows 0 (T) and 1 (B)
    // lane >=32 computed input row 2r+1 -> tile rows 2 (T) and 3 (B)
    float* wt = tile + (wib << 10);          // 1024-float wave-private region
    {
        const int sr   = lane >> 5;
        const int col8 = (lane & 31) << 3;
        float* p = wt + (sr << 9) + col8;    // tile row 2*sr, col 8*(lane&31)
        *(v4f*)(p)       = Tlo;
        *(v4f*)(p + 4)   = Thi;
        *(v4f*)(p + 256) = Blo;
        *(v4f*)(p + 260) = Bhi;
    }
    __syncthreads();

    // Read back output-linear: lane j holds cols 4j..4j+3 of each of 4 out rows.
    const float* rp = wt + (lane << 2);
    const v4f o0 = *(const v4f*)(rp);
    const v4f o1 = *(const v4f*)(rp + 256);
    const v4f o2 = *(const v4f*)(rp + 512);
    const v4f o3 = *(const v4f*)(rp + 768);

    // out[bc, 4r + tr, 4*lane ...]; row stride 256, chan stride 65536
    const int out_base = (bc << 16) + (r << 10) + (lane << 2);
    __builtin_nontemporal_store(o0, (v4f*)(out + out_base));
    __builtin_nontemporal_store(o1, (v4f*)(out + out_base + 256));
    __builtin_nontemporal_store(o2, (v4f*)(out + out_base + 512));
    __builtin_nontemporal_store(o3, (v4f*)(out + out_base + 768));
}

extern "C" void kernel_launch(void* const* d_in, const int* in_sizes, int n_in,
                              void* d_out, int out_size, void* d_ws, size_t ws_size,
                              hipStream_t stream) {
    const float* x = (const float*)d_in[0];
    float* out = (float*)d_out;
    // waves = 8 b * 64 c * 64 row-pairs = 32768; 4 waves/block -> 8192 blocks
    constexpr int blocks = 8192;
    constexpr int block = 256;
    wav_unpack_kernel<<<blocks, block, 0, stream>>>(x, out);
}